// Round 5
// baseline (340.177 us; speedup 1.0000x reference)
//
#include <hip/hip_runtime.h>

// GeneModelClassic: B=32, G=18000, K=50, L=16
//   out[b,g,l] = relu( sum_k (x[b,idx[g,k]]*sw[idx]+sb[idx]) * W[g,k,l] + bias[g,l] )
//
// R5 = R3 with compile fix: NT store via native ext_vector_type (clang's
// __builtin_nontemporal_store rejects HIP_vector_type float4*).
// One barrier per block. GT=2 genes/block (13.8 KB LDS, 9000 blocks,
// ~6 blocks/CU). Staging loads idx/sw/sb directly from global, fully
// unrolled bulk gathers. Phase 2: 2 waves/gene, float4 acc/lane, NT stores.

#define B_ 32
#define G_ 18000
#define K_ 50
#define L_ 16
#define NS_ (G_ * K_)        // 900000
#define GT 2                 // genes per block
#define COLS (GT * K_)       // 100
#define QPR (COLS / 4)       // 25 float4 slots per row
#define SLOTS (B_ * QPR)     // 800
#define XS_STRIDE 108        // floats; 432B rows (16B aligned); read conflict <=4-way
#define THREADS_ 256

typedef float f32x4_ __attribute__((ext_vector_type(4)));

__global__ __launch_bounds__(THREADS_, 6)
void gene_model_kernel(const float* __restrict__ x,
                       const float* __restrict__ sw,
                       const float* __restrict__ sb,
                       const float* __restrict__ W,
                       const float* __restrict__ bias,
                       const int*   __restrict__ sidx,
                       float*       __restrict__ out) {
  __shared__ float xs_lds[B_ * XS_STRIDE];   // 13824 B

  const int tid = (int)threadIdx.x;
  const int g0  = (int)blockIdx.x * GT;
  const int* __restrict__ idxbase = sidx + g0 * K_;

  // ---- stage: scaled xs tile (32 rows x 100 cols), single phase ----
#pragma unroll 4
  for (int j = 0; j < 4; ++j) {
    const int i = tid + j * THREADS_;
    if (i < SLOTS) {
      const int r  = i / QPR;              // b row 0..31
      const int c4 = (i - r * QPR) * 4;    // column quad base 0..96
      const int4 iv = *reinterpret_cast<const int4*>(idxbase + c4);
      const float* __restrict__ xr = x + (size_t)r * NS_;
      float4 v;
      v.x = fmaf(xr[iv.x], sw[iv.x], sb[iv.x]);
      v.y = fmaf(xr[iv.y], sw[iv.y], sb[iv.y]);
      v.z = fmaf(xr[iv.z], sw[iv.z], sb[iv.z]);
      v.w = fmaf(xr[iv.w], sw[iv.w], sb[iv.w]);
      *reinterpret_cast<float4*>(&xs_lds[r * XS_STRIDE + c4]) = v;
    }
  }
  __syncthreads();

  // ---- compute: 2 waves per gene, float4 of outputs per lane ----
  const int wave = __builtin_amdgcn_readfirstlane(tid >> 6);  // 0..3, uniform
  const int lane = tid & 63;
  const int gl   = wave >> 1;                 // local gene 0..1
  const int g    = g0 + gl;
  const int b    = lane & 31;
  const int l0   = (wave & 1) * 8 + (lane >> 5) * 4;   // 0,4,8,12

  const float* __restrict__ Wg  = W + (size_t)g * (K_ * L_) + l0;
  const float* __restrict__ xsp = &xs_lds[b * XS_STRIDE + gl * K_];

  float4 acc = *reinterpret_cast<const float4*>(bias + (size_t)g * L_ + l0);

#pragma unroll 10
  for (int k = 0; k < K_; ++k) {
    const float  xv = xsp[k];
    const float4 w4 = *reinterpret_cast<const float4*>(Wg + k * L_);
    acc.x = fmaf(xv, w4.x, acc.x);
    acc.y = fmaf(xv, w4.y, acc.y);
    acc.z = fmaf(xv, w4.z, acc.z);
    acc.w = fmaf(xv, w4.w, acc.w);
  }

  f32x4_ o;
  o.x = fmaxf(acc.x, 0.f); o.y = fmaxf(acc.y, 0.f);
  o.z = fmaxf(acc.z, 0.f); o.w = fmaxf(acc.w, 0.f);

  float* op = out + (size_t)b * (G_ * L_) + (size_t)g * L_ + l0;
  __builtin_nontemporal_store(o, reinterpret_cast<f32x4_*>(op));
}

extern "C" void kernel_launch(void* const* d_in, const int* in_sizes, int n_in,
                              void* d_out, int out_size, void* d_ws, size_t ws_size,
                              hipStream_t stream) {
  const float* x    = (const float*)d_in[0];
  const float* sw   = (const float*)d_in[1];
  const float* sb   = (const float*)d_in[2];
  const float* W    = (const float*)d_in[3];
  const float* bias = (const float*)d_in[4];
  const int*   sidx = (const int*)d_in[5];
  float*       out  = (float*)d_out;

  dim3 grid(G_ / GT);      // 9000 blocks
  dim3 block(THREADS_);    // 256 threads = 4 waves
  gene_model_kernel<<<grid, block, 0, stream>>>(x, sw, sb, W, bias, sidx, out);
}